// Round 4
// baseline (349.918 us; speedup 1.0000x reference)
//
#include <hip/hip_runtime.h>
#include <hip/hip_bf16.h>

typedef unsigned short u16;
typedef __attribute__((ext_vector_type(8))) short b16x8;   // 8 bf16 (MFMA A/B frag)
typedef __attribute__((ext_vector_type(4))) float f32x4;   // MFMA C/D frag

__device__ __forceinline__ u16 f2bf(float f) {
    union { float f; unsigned int u; } v; v.f = f;
    unsigned int u = v.u;
    return (u16)((u + 0x7FFFu + ((u >> 16) & 1u)) >> 16);
}

// ---------------------------------------------------------------------------
// K0: pack weights to bf16 [n][k], XOR-swizzled 16B chunks (chunk ^= n&7) so
//     K1/K3 can stage LINEARLY and read swizzled. 16 blocks.
// ---------------------------------------------------------------------------
__global__ __launch_bounds__(256) void k_pack_w(const float* __restrict__ w0,
                                                const float* __restrict__ w1,
                                                const float* __restrict__ w2,
                                                const float* __restrict__ w3,
                                                u16* __restrict__ dstbase) {
    const int b = blockIdx.x;                 // tensor = b>>2, quarter = b&3
    const int tensor = b >> 2;
    const float* src = (tensor == 0) ? w0 : (tensor == 1) ? w1
                     : (tensor == 2) ? w2 : w3;
    u16* dst = dstbase + tensor * 16384;
    const int i0 = (b & 3) * 4096;
    for (int j = threadIdx.x; j < 4096; j += 256) {
        int i = i0 + j;
        int k = i >> 7, n = i & 127;          // src is [k][n]
        int kc = k >> 3, kr = k & 7;
        dst[n * 128 + ((kc ^ (n & 7)) << 3) + kr] = f2bf(src[i]);
    }
}

// ---------------------------------------------------------------------------
// K1: LayerNorm + QKV projection. grid (768, 3), 512 threads, 128 tokens/block
//     (blocks never straddle a window since 384 = 3*128).
//     Q,K -> [l][t][128] bf16 (coalesced via wave-local LDS round-trip).
//     V   -> transposed [l][h][dh][t] bf16 (via in-LDS transpose).
// ---------------------------------------------------------------------------
struct K1Args {
    const float* x[3];
    const float* lng[3];
    const float* lnb[3];
    const float* bias[3];
    u16* outQ; u16* outK; u16* outVt;
};

__global__ __launch_bounds__(512, 4) void k_ln_proj(K1Args a, const u16* __restrict__ wt) {
    __shared__ u16 sW[16384];   // 32 KB, pre-swizzled by K0
    __shared__ u16 sA[16384];   // 128 x 128 bf16, chunk-XOR swizzled
    const int tid = threadIdx.x;
    const int tensor = blockIdx.y;
    const int wv = tid >> 6;

    // stage W (linear copy; swizzle already in layout)
    const u16* wsrc = wt + tensor * 16384;
#pragma unroll
    for (int it = 0; it < 4; ++it) {
        int e = (it * 512 + tid) << 3;
        *(b16x8*)(sW + e) = *(const b16x8*)(wsrc + e);
    }

    // LayerNorm: 4 lanes per token, 128 tokens
    const int r = tid >> 2, sub = tid & 3;
    const int token0 = blockIdx.x * 128;
    const int l = token0 / 384;
    const int tloc0 = token0 % 384;           // 0,128,256
    const int ti = tloc0 + r;
    const int nn = ti >> 6, w = ti & 63;
    const float* rowp = a.x[tensor] + (size_t)(nn * 16384 + l * 64 + w) * 128 + sub * 32;
    float v[32];
    float s = 0.f, s2 = 0.f;
#pragma unroll
    for (int j = 0; j < 32; j += 4) {
        float4 f = *(const float4*)(rowp + j);
        v[j] = f.x; v[j + 1] = f.y; v[j + 2] = f.z; v[j + 3] = f.w;
        s  += (f.x + f.y) + (f.z + f.w);
        s2 += (f.x * f.x + f.y * f.y) + (f.z * f.z + f.w * f.w);
    }
    s  += __shfl_xor(s, 1);  s  += __shfl_xor(s, 2);
    s2 += __shfl_xor(s2, 1); s2 += __shfl_xor(s2, 2);
    const float mean = s * (1.f / 128.f);
    const float rstd = rsqrtf(s2 * (1.f / 128.f) - mean * mean + 1e-5f);
    const float* gp = a.lng[tensor];
    const float* bbp = a.lnb[tensor];
#pragma unroll
    for (int j = 0; j < 32; j += 8) {
        int k0 = sub * 32 + j;
        b16x8 tv;
#pragma unroll
        for (int q = 0; q < 8; ++q) {
            int k = k0 + q;
            tv[q] = (short)f2bf((v[j + q] - mean) * rstd * gp[k] + bbp[k]);
        }
        *(b16x8*)(sA + r * 128 + (((k0 >> 3) ^ (r & 7)) << 3)) = tv;
    }
    __syncthreads();

    // MFMA: wave wv owns rows [wv*16, wv*16+16); 4 ktiles x 8 ntiles
    const int lane = tid & 63, lr = lane & 15, lg = lane >> 4;
    f32x4 acc[8];
#pragma unroll
    for (int i = 0; i < 8; ++i) acc[i] = (f32x4){0.f, 0.f, 0.f, 0.f};
    const int rowA = wv * 16 + lr;
#pragma unroll
    for (int kt = 0; kt < 4; ++kt) {
        const int ch = kt * 4 + lg;
        b16x8 af = *(const b16x8*)(sA + rowA * 128 + ((ch ^ (rowA & 7)) << 3));
#pragma unroll
        for (int nt = 0; nt < 8; ++nt) {
            const int nc = nt * 16 + lr;
            b16x8 bf = *(const b16x8*)(sW + nc * 128 + ((ch ^ (nc & 7)) << 3));
            acc[nt] = __builtin_amdgcn_mfma_f32_16x16x32_bf16(af, bf, acc[nt], 0, 0, 0);
        }
    }

    const float* biasp = a.bias[tensor];
    if (tensor != 2) {
        // Q/K epilogue: wave-local LDS round-trip (own rows only -> no barrier)
        const float scale = (tensor == 0) ? 0.17677669529663687f : 1.0f;
        u16* outp = (tensor == 0) ? a.outQ : a.outK;
#pragma unroll
        for (int nt = 0; nt < 8; ++nt) {
            const int col = nt * 16 + lr;
            const float bb = biasp[col];
#pragma unroll
            for (int rg = 0; rg < 4; ++rg) {
                const int rowl = wv * 16 + lg * 4 + rg;
                float val = (acc[nt][rg] + bb) * scale;
                int cch = col >> 3;
                sA[rowl * 128 + ((cch ^ (rowl & 7)) << 3) + (col & 7)] = f2bf(val);
            }
        }
        // read back coalesced (same wave's rows; LDS ops are wave-ordered)
        const int rrow = wv * 16 + (lane >> 2);
#pragma unroll
        for (int c = 0; c < 4; ++c) {
            int colc = (lane & 3) + c * 4;    // 16B chunks, 64B-contiguous per 4 lanes
            b16x8 val = *(const b16x8*)(sA + rrow * 128 + ((colc ^ (rrow & 7)) << 3));
            *(b16x8*)(outp + (size_t)(token0 + rrow) * 128 + colc * 8) = val;
        }
    } else {
        // V epilogue: transpose via LDS to [l][h][dh][t]
        __syncthreads();     // everyone done reading sA fragments
#pragma unroll
        for (int nt = 0; nt < 8; ++nt) {
            const int col = nt * 16 + lr;     // feature 0..127
            const float bb = biasp[col];
#pragma unroll
            for (int rg = 0; rg < 4; ++rg) {
                const int trowl = wv * 16 + lg * 4 + rg;   // local t
                float val = acc[nt][rg] + bb;
                int tch = trowl >> 3;
                sA[col * 128 + ((tch ^ (col & 7)) << 3) + (trowl & 7)] = f2bf(val);
            }
        }
        __syncthreads();
        const int f = tid >> 2;               // feature 0..127
        const size_t vb = ((size_t)(l * 4 + (f >> 5)) * 32 + (f & 31)) * 384 + tloc0;
#pragma unroll
        for (int c = 0; c < 4; ++c) {
            int tch = (tid & 3) + c * 4;
            b16x8 val = *(const b16x8*)(sA + f * 128 + ((tch ^ (f & 7)) << 3));
            *(b16x8*)(a.outVt + vb + tch * 8) = val;
        }
    }
}

// ---------------------------------------------------------------------------
// K2: per-(window, head) attention. grid (256,4), 256 threads, 6 qtiles/wave.
//     LDS ~37.9 KB -> 3-4 blocks/CU. V^T read straight from global (L2-hot).
// ---------------------------------------------------------------------------
__global__ __launch_bounds__(256, 3) void k_attn(const u16* __restrict__ qh,
                                                 const u16* __restrict__ kh,
                                                 const u16* __restrict__ vt,
                                                 u16* __restrict__ ah) {
    __shared__ u16 sK[384 * 32];        // [t][dh], chunk ^= t&3 swizzle
    __shared__ u16 sP[4][16 * 104];     // per-wave P chunk, stride 104 (bank-free reads)
    const int tid = threadIdx.x;
    const int l = blockIdx.x, h = blockIdx.y;
    const size_t baseQ = ((size_t)l * 384) * 128 + h * 32;
    const size_t baseV = ((size_t)(l * 4 + h) * 32) * 384;

    // stage K only (row-major, swizzled chunks)
#pragma unroll
    for (int it = 0; it < 6; ++it) {
        int idx = it * 256 + tid;             // 0..1535
        int t = idx >> 2, c = idx & 3;
        b16x8 kv = *(const b16x8*)(kh + baseQ + (size_t)t * 128 + c * 8);
        *(b16x8*)(sK + t * 32 + ((c ^ (t & 3)) << 3)) = kv;
    }
    __syncthreads();

    const int wv = tid >> 6, lane = tid & 63, lr = lane & 15, lg = lane >> 4;
    u16* myP = sP[wv];

    for (int qt = wv; qt < 24; qt += 4) {
        b16x8 qf = *(const b16x8*)(qh + baseQ + (size_t)(qt * 16 + lr) * 128 + lg * 8);
        f32x4 sacc[24];
#pragma unroll
        for (int kt = 0; kt < 24; ++kt) {
            const int t = kt * 16 + lr;
            b16x8 kf = *(const b16x8*)(sK + t * 32 + ((lg ^ (t & 3)) << 3));
            sacc[kt] = __builtin_amdgcn_mfma_f32_16x16x32_bf16(
                qf, kf, (f32x4){0.f, 0.f, 0.f, 0.f}, 0, 0, 0);
        }
        // softmax over t: row q = lg*4+rg lives in 16 lanes (lr) x 24 regs
        float sm[4];
#pragma unroll
        for (int rg = 0; rg < 4; ++rg) {
            float m = sacc[0][rg];
#pragma unroll
            for (int kt = 1; kt < 24; ++kt) m = fmaxf(m, sacc[kt][rg]);
            m = fmaxf(m, __shfl_xor(m, 1));
            m = fmaxf(m, __shfl_xor(m, 2));
            m = fmaxf(m, __shfl_xor(m, 4));
            m = fmaxf(m, __shfl_xor(m, 8));
            float ss = 0.f;
#pragma unroll
            for (int kt = 0; kt < 24; ++kt) {
                float e = __expf(sacc[kt][rg] - m);
                sacc[kt][rg] = e;
                ss += e;
            }
            ss += __shfl_xor(ss, 1); ss += __shfl_xor(ss, 2);
            ss += __shfl_xor(ss, 4); ss += __shfl_xor(ss, 8);
            sm[rg] = ss;
        }
        // PV in 4 chunks of 96 tokens through per-wave P buffer
        f32x4 pacc[2];
        pacc[0] = (f32x4){0.f, 0.f, 0.f, 0.f};
        pacc[1] = (f32x4){0.f, 0.f, 0.f, 0.f};
#pragma unroll
        for (int chunk = 0; chunk < 4; ++chunk) {
#pragma unroll
            for (int kc = 0; kc < 6; ++kc) {
                const int kt = chunk * 6 + kc;
#pragma unroll
                for (int rg = 0; rg < 4; ++rg) {
                    int q = lg * 4 + rg;
                    int tl = kc * 16 + lr;         // 0..95
                    myP[q * 104 + tl] = f2bf(sacc[kt][rg]);
                }
            }
            // same-wave write->read (LDS ops wave-ordered; compiler waits lgkm)
#pragma unroll
            for (int k2 = 0; k2 < 3; ++k2) {
                b16x8 pf = *(const b16x8*)(myP + lr * 104 + k2 * 32 + lg * 8);
#pragma unroll
                for (int nt = 0; nt < 2; ++nt) {
                    b16x8 vf = *(const b16x8*)(vt + baseV +
                                               (size_t)(nt * 16 + lr) * 384 +
                                               chunk * 96 + k2 * 32 + lg * 8);
                    pacc[nt] = __builtin_amdgcn_mfma_f32_16x16x32_bf16(pf, vf, pacc[nt], 0, 0, 0);
                }
            }
        }
        // epilogue: normalize by row sum, store to [l][t][h*32+dh]
#pragma unroll
        for (int nt = 0; nt < 2; ++nt) {
#pragma unroll
            for (int rg = 0; rg < 4; ++rg) {
                float aa = pacc[nt][rg] / sm[rg];
                size_t trow = (size_t)(qt * 16 + lg * 4 + rg);
                ah[baseQ + trow * 128 + nt * 16 + lr] = f2bf(aa);
            }
        }
    }
}

// ---------------------------------------------------------------------------
// K3: z = a @ Wp + bp with mean over n folded into the accumulator.
//     512 threads = 8 waves: wave = (wm 0..3, wn 0..1); 96 MFMA/wave.
// ---------------------------------------------------------------------------
__global__ __launch_bounds__(512, 2) void k_proj_mean(const u16* __restrict__ ah,
                                                      const u16* __restrict__ wtp,
                                                      const float* __restrict__ bp,
                                                      float* __restrict__ out) {
    __shared__ u16 sW[16384];
    const int tid = threadIdx.x;
    const int l = blockIdx.x;
#pragma unroll
    for (int it = 0; it < 4; ++it) {
        int e = (it * 512 + tid) << 3;
        *(b16x8*)(sW + e) = *(const b16x8*)(wtp + e);
    }
    __syncthreads();
    const int wv8 = tid >> 6;
    const int wm = wv8 >> 1, wn = wv8 & 1;
    const int lane = tid & 63, lr = lane & 15, lg = lane >> 4;
    f32x4 acc[4];
#pragma unroll
    for (int i = 0; i < 4; ++i) acc[i] = (f32x4){0.f, 0.f, 0.f, 0.f};
#pragma unroll
    for (int nn = 0; nn < 6; ++nn) {
        const int mt = wm + nn * 4;            // t-tile: w-rows [wm*16, wm*16+16), n = nn
        const size_t rowb = ((size_t)l * 384 + mt * 16 + lr) * 128;
#pragma unroll
        for (int kt = 0; kt < 4; ++kt) {
            b16x8 af = *(const b16x8*)(ah + rowb + kt * 32 + lg * 8);
            const int ch = kt * 4 + lg;
#pragma unroll
            for (int nt = 0; nt < 4; ++nt) {
                const int nc = (wn * 4 + nt) * 16 + lr;
                b16x8 bf = *(const b16x8*)(sW + nc * 128 + ((ch ^ (nc & 7)) << 3));
                acc[nt] = __builtin_amdgcn_mfma_f32_16x16x32_bf16(af, bf, acc[nt], 0, 0, 0);
            }
        }
    }
#pragma unroll
    for (int nt = 0; nt < 4; ++nt) {
        const int col = (wn * 4 + nt) * 16 + lr;
        const float bb = bp[col];
#pragma unroll
        for (int rg = 0; rg < 4; ++rg) {
            const int wrow = wm * 16 + lg * 4 + rg;
            out[((size_t)l * 64 + wrow) * 128 + col] = acc[nt][rg] * (1.0f / 6.0f) + bb;
        }
    }
}

// ---------------------------------------------------------------------------
extern "C" void kernel_launch(void* const* d_in, const int* in_sizes, int n_in,
                              void* d_out, int out_size, void* d_ws, size_t ws_size,
                              hipStream_t stream) {
    (void)in_sizes; (void)n_in; (void)out_size; (void)ws_size;
    const float* q      = (const float*)d_in[0];
    const float* k      = (const float*)d_in[1];
    const float* v      = (const float*)d_in[2];
    const float* ln_q_g = (const float*)d_in[3];
    const float* ln_q_b = (const float*)d_in[4];
    const float* ln_k_g = (const float*)d_in[5];
    const float* ln_k_b = (const float*)d_in[6];
    const float* ln_v_g = (const float*)d_in[7];
    const float* ln_v_b = (const float*)d_in[8];
    const float* Wq     = (const float*)d_in[9];
    const float* bq     = (const float*)d_in[10];
    const float* Wk     = (const float*)d_in[11];
    const float* bk     = (const float*)d_in[12];
    const float* Wv     = (const float*)d_in[13];
    const float* bv     = (const float*)d_in[14];
    const float* Wp     = (const float*)d_in[15];
    const float* bp     = (const float*)d_in[16];
    float* out = (float*)d_out;

    u16* ws = (u16*)d_ws;
    const long long MATE = 98304LL * 128;
    u16* wQ  = ws;
    u16* wK  = ws + MATE;
    u16* wVt = ws + 2 * MATE;               // transposed V: [l][h][32][384]
    u16* wA  = ws + 3 * MATE;
    u16* wWt = ws + 4 * MATE;               // 4 x 16384 packed swizzled weights

    k_pack_w<<<16, 256, 0, stream>>>(Wq, Wk, Wv, Wp, wWt);

    K1Args args;
    args.x[0] = q;       args.x[1] = k;       args.x[2] = v;
    args.lng[0] = ln_q_g; args.lng[1] = ln_k_g; args.lng[2] = ln_v_g;
    args.lnb[0] = ln_q_b; args.lnb[1] = ln_k_b; args.lnb[2] = ln_v_b;
    args.bias[0] = bq;   args.bias[1] = bk;   args.bias[2] = bv;
    args.outQ = wQ;      args.outK = wK;      args.outVt = wVt;
    k_ln_proj<<<dim3(768, 3), 512, 0, stream>>>(args, wWt);

    k_attn<<<dim3(256, 4), 256, 0, stream>>>(wQ, wK, wVt, wA);

    k_proj_mean<<<256, 512, 0, stream>>>(wA, wWt + 3 * 16384, bp, out);
}